// Round 2
// baseline (942.704 us; speedup 1.0000x reference)
//
#include <hip/hip_runtime.h>
#include <hip/hip_bf16.h>

// ---------------------------------------------------------------------------
// AlsoDecoder: probs = softmax(MLP(concat(feats[col], also_pts[row]-pcd[col])))
// Algebraic folding: x@w_in = feats[col]@W_f + (also_pts[row]-pcd[col])@W_p
//                          = S[col] + Q[row]
//   S[n] = feats[n]@W_f - pcd[n]@W_p          (precomputed per source point)
//   Q[m] = also_pts[m]@W_p + b_in             (precomputed per query point)
// Stored bf16 in d_ws. Edge kernel: h1=relu(S+Q); relu(h1@w1+b1);
// x3 = (...)@w2+b2 (NO relu on x3 — reference is act-then-linear);
// logits = x3@w_out+b_out; softmax; plus label gather.
// ---------------------------------------------------------------------------

__device__ __forceinline__ float bflo(unsigned int u) {
    return __uint_as_float(u << 16);
}
__device__ __forceinline__ float bfhi(unsigned int u) {
    return __uint_as_float(u & 0xffff0000u);
}

// S[n][j] = sum_k feats[n][k]*w_in[k][j] - sum_k pcd[n][k]*w_in[64+k][j]
__global__ __launch_bounds__(256) void precompute_S(
    const float* __restrict__ feats, const float* __restrict__ pcd,
    const float* __restrict__ w_in, __hip_bfloat16* __restrict__ S, int N) {
    int t = blockIdx.x * 256 + threadIdx.x;
    int p = t >> 6, j = t & 63;
    if (p >= N) return;
    const float* f = feats + (size_t)p * 64;
    float acc = 0.f;
#pragma unroll
    for (int k = 0; k < 64; ++k) acc = fmaf(f[k], w_in[k * 64 + j], acc);
    const float* pp = pcd + (size_t)p * 3;
#pragma unroll
    for (int k = 0; k < 3; ++k) acc = fmaf(-pp[k], w_in[(64 + k) * 64 + j], acc);
    S[t] = __float2bfloat16(acc);
}

// Q[m][j] = sum_k also_pts[m][k]*w_in[64+k][j] + b_in[j]
__global__ __launch_bounds__(256) void precompute_Q(
    const float* __restrict__ also_pts, const float* __restrict__ w_in,
    const float* __restrict__ b_in, __hip_bfloat16* __restrict__ Q, int M) {
    int t = blockIdx.x * 256 + threadIdx.x;
    int m = t >> 6, j = t & 63;
    if (m >= M) return;
    const float* q = also_pts + (size_t)m * 3;
    float acc = b_in[j];
#pragma unroll
    for (int k = 0; k < 3; ++k) acc = fmaf(q[k], w_in[(64 + k) * 64 + j], acc);
    Q[t] = __float2bfloat16(acc);
}

__global__ __launch_bounds__(256) void edge_mlp(
    const __hip_bfloat16* __restrict__ S, const __hip_bfloat16* __restrict__ Q,
    const int* __restrict__ row, const int* __restrict__ col,
    const int* __restrict__ labels,
    const float* __restrict__ w1, const float* __restrict__ b1,
    const float* __restrict__ w2, const float* __restrict__ b2,
    const float* __restrict__ w_out, const float* __restrict__ b_out,
    float* __restrict__ out, int E) {
    __shared__ float w1s[64 * 64];
    __shared__ float w2s[64 * 64];
    __shared__ float b1s[64], b2s[64], wos[128], bos[2];

    for (int i = threadIdx.x; i < 4096; i += 256) {
        w1s[i] = w1[i];
        w2s[i] = w2[i];
    }
    if (threadIdx.x < 64) {
        b1s[threadIdx.x] = b1[threadIdx.x];
        b2s[threadIdx.x] = b2[threadIdx.x];
    }
    if (threadIdx.x < 128) wos[threadIdx.x] = w_out[threadIdx.x];
    if (threadIdx.x < 2) bos[threadIdx.x] = b_out[threadIdx.x];
    __syncthreads();

    int e = blockIdx.x * 256 + threadIdx.x;
    if (e >= E) return;

    int r = row[e];
    int c = col[e];

    // h1 = relu(x1) where x1 = S[c] + Q[r]
    float x[64];
    {
        const uint4* sp = (const uint4*)(S + (size_t)c * 64);
        const uint4* qp = (const uint4*)(Q + (size_t)r * 64);
#pragma unroll
        for (int i = 0; i < 8; ++i) {
            uint4 sv = sp[i];
            uint4 qv = qp[i];
            x[i * 8 + 0] = fmaxf(bflo(sv.x) + bflo(qv.x), 0.f);
            x[i * 8 + 1] = fmaxf(bfhi(sv.x) + bfhi(qv.x), 0.f);
            x[i * 8 + 2] = fmaxf(bflo(sv.y) + bflo(qv.y), 0.f);
            x[i * 8 + 3] = fmaxf(bfhi(sv.y) + bfhi(qv.y), 0.f);
            x[i * 8 + 4] = fmaxf(bflo(sv.z) + bflo(qv.z), 0.f);
            x[i * 8 + 5] = fmaxf(bfhi(sv.z) + bfhi(qv.z), 0.f);
            x[i * 8 + 6] = fmaxf(bflo(sv.w) + bflo(qv.w), 0.f);
            x[i * 8 + 7] = fmaxf(bfhi(sv.w) + bfhi(qv.w), 0.f);
        }
    }

    // x2 = x @ w1 + b1 ; y = relu(x2)
    float y[64];
#pragma unroll
    for (int jt = 0; jt < 16; ++jt) {
        float4 acc = *(const float4*)(&b1s[jt * 4]);
#pragma unroll
        for (int k = 0; k < 64; ++k) {
            float4 w = *(const float4*)(&w1s[k * 64 + jt * 4]);
            acc.x = fmaf(x[k], w.x, acc.x);
            acc.y = fmaf(x[k], w.y, acc.y);
            acc.z = fmaf(x[k], w.z, acc.z);
            acc.w = fmaf(x[k], w.w, acc.w);
        }
        y[jt * 4 + 0] = fmaxf(acc.x, 0.f);
        y[jt * 4 + 1] = fmaxf(acc.y, 0.f);
        y[jt * 4 + 2] = fmaxf(acc.z, 0.f);
        y[jt * 4 + 3] = fmaxf(acc.w, 0.f);
    }

    // x3 = y @ w2 + b2   (NO relu — reference applies relu only before w1/w2)
#pragma unroll
    for (int jt = 0; jt < 16; ++jt) {
        float4 acc = *(const float4*)(&b2s[jt * 4]);
#pragma unroll
        for (int k = 0; k < 64; ++k) {
            float4 w = *(const float4*)(&w2s[k * 64 + jt * 4]);
            acc.x = fmaf(y[k], w.x, acc.x);
            acc.y = fmaf(y[k], w.y, acc.y);
            acc.z = fmaf(y[k], w.z, acc.z);
            acc.w = fmaf(y[k], w.w, acc.w);
        }
        x[jt * 4 + 0] = acc.x;
        x[jt * 4 + 1] = acc.y;
        x[jt * 4 + 2] = acc.z;
        x[jt * 4 + 3] = acc.w;
    }

    // output layer: logits = x3 @ w_out + b_out  (w_out is [64][2] row-major)
    float l0 = bos[0], l1 = bos[1];
#pragma unroll
    for (int f = 0; f < 64; ++f) {
        l0 = fmaf(x[f], wos[f * 2 + 0], l0);
        l1 = fmaf(x[f], wos[f * 2 + 1], l1);
    }

    // softmax over 2 classes
    float mx = fmaxf(l0, l1);
    float e0 = __expf(l0 - mx);
    float e1 = __expf(l1 - mx);
    float inv = 1.f / (e0 + e1);
    float2 pr = make_float2(e0 * inv, e1 * inv);
    *(float2*)(out + (size_t)2 * e) = pr;

    // second output: also_labels[row[e]] as float
    out[(size_t)2 * E + e] = (float)labels[r];
}

extern "C" void kernel_launch(void* const* d_in, const int* in_sizes, int n_in,
                              void* d_out, int out_size, void* d_ws, size_t ws_size,
                              hipStream_t stream) {
    const float* pcd       = (const float*)d_in[0];
    const float* feats     = (const float*)d_in[1];
    const float* also_pts  = (const float*)d_in[2];
    const int*   labels    = (const int*)d_in[3];
    const int*   row       = (const int*)d_in[4];
    const int*   col       = (const int*)d_in[5];
    const float* w_in      = (const float*)d_in[6];
    const float* b_in      = (const float*)d_in[7];
    const float* w1        = (const float*)d_in[8];
    const float* b1        = (const float*)d_in[9];
    const float* w2        = (const float*)d_in[10];
    const float* b2        = (const float*)d_in[11];
    const float* w_out     = (const float*)d_in[12];
    const float* b_out     = (const float*)d_in[13];

    int N = in_sizes[0] / 3;
    int M = in_sizes[2] / 3;
    int E = in_sizes[4];

    __hip_bfloat16* Sb = (__hip_bfloat16*)d_ws;
    __hip_bfloat16* Qb = Sb + (size_t)N * 64;

    int gS = (N * 64 + 255) / 256;
    int gQ = (M * 64 + 255) / 256;
    int gE = (E + 255) / 256;

    precompute_S<<<gS, 256, 0, stream>>>(feats, pcd, w_in, Sb, N);
    precompute_Q<<<gQ, 256, 0, stream>>>(also_pts, w_in, b_in, Qb, M);
    edge_mlp<<<gE, 256, 0, stream>>>(Sb, Qb, row, col, labels,
                                     w1, b1, w2, b2, w_out, b_out,
                                     (float*)d_out, E);
}

// Round 3
// 218.691 us; speedup vs baseline: 4.3107x; 4.3107x over previous
//
#include <hip/hip_runtime.h>
#include <hip/hip_bf16.h>

// ---------------------------------------------------------------------------
// AlsoDecoder via algebraic folding + MFMA:
//   x1 = concat(feats[col], also_pts[row]-pcd[col]) @ w_in + b_in
//      = S[col] + Q[row]                (S,Q precomputed per point, bf16)
//   y  = relu( relu(x1) @ W1 + b1 )     (MFMA 16x16x32 bf16, 16 edges/wave)
//   logits = y @ (W2@W_out) + (b2@W_out + b_out)   (layer-3 folded: no relu on x3)
//   probs = softmax(logits)
// ---------------------------------------------------------------------------

typedef __attribute__((ext_vector_type(8))) short short8v;   // 8 bf16
typedef __attribute__((ext_vector_type(4))) float f32x4;

union U84 { uint4 u; short8v s; };

__device__ __forceinline__ float bflo(unsigned int u) { return __uint_as_float(u << 16); }
__device__ __forceinline__ float bfhi(unsigned int u) { return __uint_as_float(u & 0xffff0000u); }
__device__ __forceinline__ unsigned short bfbits(float f) {
    __hip_bfloat16 h = __float2bfloat16(f);
    return *reinterpret_cast<unsigned short*>(&h);
}
// pack relu(s+q) of two bf16 pairs into one dword of 2 bf16
__device__ __forceinline__ unsigned pk2(unsigned su, unsigned qu) {
    float lo = fmaxf(bflo(su) + bflo(qu), 0.f);
    float hi = fmaxf(bfhi(su) + bfhi(qu), 0.f);
    return (unsigned)bfbits(lo) | ((unsigned)bfbits(hi) << 16);
}

// ---------------- prep kernels -------------------------------------------
// S[n][j] = feats[n]@W_f - pcd[n]@W_p
__global__ __launch_bounds__(256) void precompute_S(
    const float* __restrict__ feats, const float* __restrict__ pcd,
    const float* __restrict__ w_in, __hip_bfloat16* __restrict__ S, int N) {
    int t = blockIdx.x * 256 + threadIdx.x;
    int p = t >> 6, j = t & 63;
    if (p >= N) return;
    const float* f = feats + (size_t)p * 64;
    float acc = 0.f;
#pragma unroll
    for (int k = 0; k < 64; ++k) acc = fmaf(f[k], w_in[k * 64 + j], acc);
    const float* pp = pcd + (size_t)p * 3;
#pragma unroll
    for (int k = 0; k < 3; ++k) acc = fmaf(-pp[k], w_in[(64 + k) * 64 + j], acc);
    S[t] = __float2bfloat16(acc);
}

// Q[m][j] = also_pts[m]@W_p + b_in
__global__ __launch_bounds__(256) void precompute_Q(
    const float* __restrict__ also_pts, const float* __restrict__ w_in,
    const float* __restrict__ b_in, __hip_bfloat16* __restrict__ Q, int M) {
    int t = blockIdx.x * 256 + threadIdx.x;
    int m = t >> 6, j = t & 63;
    if (m >= M) return;
    const float* q = also_pts + (size_t)m * 3;
    float acc = b_in[j];
#pragma unroll
    for (int k = 0; k < 3; ++k) acc = fmaf(q[k], w_in[(64 + k) * 64 + j], acc);
    Q[t] = __float2bfloat16(acc);
}

// Pack W1 into per-lane B-fragment order for mfma_f32_16x16x32_bf16.
// frag f = ntile*2 + kstep; slot (lane, j) <- W1[kstep*32 + 8*(lane>>4) + j]
//                                              [ntile*16 + (lane&15)]
__global__ __launch_bounds__(256) void pack_w1(
    const float* __restrict__ w1, short* __restrict__ dst) {
    int t = blockIdx.x * 256 + threadIdx.x;   // 4096 total
    if (t >= 4096) return;
    int f = t >> 9, lane = (t >> 3) & 63, j = t & 7;
    int ntile = f >> 1, kstep = f & 1;
    int k = kstep * 32 + ((lane >> 4) << 3) + j;
    int n = ntile * 16 + (lane & 15);
    dst[t] = (short)bfbits(w1[k * 64 + n]);
}

// wfold[n][c] = sum_m W2[n][m]*Wout[m][c];  bfold[c] = b2@Wout[:,c] + bout[c]
__global__ __launch_bounds__(256) void fold_wout(
    const float* __restrict__ w2, const float* __restrict__ w_out,
    const float* __restrict__ b2, const float* __restrict__ b_out,
    float* __restrict__ wfold, float* __restrict__ bfold) {
    int t = threadIdx.x;
    if (t < 128) {
        int n = t >> 1, c = t & 1;
        float acc = 0.f;
#pragma unroll
        for (int m = 0; m < 64; ++m) acc = fmaf(w2[n * 64 + m], w_out[m * 2 + c], acc);
        wfold[t] = acc;
    } else if (t < 130) {
        int c = t - 128;
        float acc = b_out[c];
#pragma unroll
        for (int m = 0; m < 64; ++m) acc = fmaf(b2[m], w_out[m * 2 + c], acc);
        bfold[c] = acc;
    }
}

// ---------------- edge kernel --------------------------------------------
__global__ __launch_bounds__(256) void edge_mfma(
    const __hip_bfloat16* __restrict__ S, const __hip_bfloat16* __restrict__ Q,
    const int* __restrict__ row, const int* __restrict__ col,
    const int* __restrict__ labels,
    const short8v* __restrict__ w1frag,     // [8 frags][64 lanes] short8
    const float* __restrict__ wfold, const float* __restrict__ bfold,
    const float* __restrict__ b1,
    float* __restrict__ out, int E, int ngroups) {
    int lane = threadIdx.x & 63;
    int idx  = lane & 15;          // edge-in-group for A; n-in-tile for C
    int g    = lane >> 4;          // k-chunk group / C row group
    int gwave  = blockIdx.x * 4 + (threadIdx.x >> 6);
    int nwaves = gridDim.x * 4;

    // per-wave constants (held in registers across the grid-stride loop)
    short8v wf[8];
#pragma unroll
    for (int f = 0; f < 8; ++f) wf[f] = w1frag[f * 64 + lane];
    float b1v[4], wf0[4], wf1[4];
#pragma unroll
    for (int t = 0; t < 4; ++t) {
        b1v[t] = b1[t * 16 + idx];
        wf0[t] = wfold[(t * 16 + idx) * 2 + 0];
        wf1[t] = wfold[(t * 16 + idx) * 2 + 1];
    }
    float bf0 = bfold[0], bf1 = bfold[1];

    for (int grp = gwave; grp < ngroups; grp += nwaves) {
        int base = grp << 4;
        int e = base + idx;
        int eok = (e < E);
        int esafe = eok ? e : (E - 1);
        int r = row[esafe];
        int c = col[esafe];

        // gather + h1 = relu(S[c]+Q[r]) packed into A-frags (k = 8*g + j)
        const uint4* sp = (const uint4*)(S + (size_t)c * 64);
        const uint4* qp = (const uint4*)(Q + (size_t)r * 64);
        uint4 s0 = sp[g], q0 = qp[g];          // k in [0,32)
        uint4 s1 = sp[4 + g], q1 = qp[4 + g];  // k in [32,64)
        U84 a0, a1;
        a0.u.x = pk2(s0.x, q0.x); a0.u.y = pk2(s0.y, q0.y);
        a0.u.z = pk2(s0.z, q0.z); a0.u.w = pk2(s0.w, q0.w);
        a1.u.x = pk2(s1.x, q1.x); a1.u.y = pk2(s1.y, q1.y);
        a1.u.z = pk2(s1.z, q1.z); a1.u.w = pk2(s1.w, q1.w);

        // Y = X @ W1 + b1  (rows = 16 edges, cols = 64) via 8 MFMAs
        f32x4 acc0 = {b1v[0], b1v[0], b1v[0], b1v[0]};
        f32x4 acc1 = {b1v[1], b1v[1], b1v[1], b1v[1]};
        f32x4 acc2 = {b1v[2], b1v[2], b1v[2], b1v[2]};
        f32x4 acc3 = {b1v[3], b1v[3], b1v[3], b1v[3]};
        acc0 = __builtin_amdgcn_mfma_f32_16x16x32_bf16(a0.s, wf[0], acc0, 0, 0, 0);
        acc0 = __builtin_amdgcn_mfma_f32_16x16x32_bf16(a1.s, wf[1], acc0, 0, 0, 0);
        acc1 = __builtin_amdgcn_mfma_f32_16x16x32_bf16(a0.s, wf[2], acc1, 0, 0, 0);
        acc1 = __builtin_amdgcn_mfma_f32_16x16x32_bf16(a1.s, wf[3], acc1, 0, 0, 0);
        acc2 = __builtin_amdgcn_mfma_f32_16x16x32_bf16(a0.s, wf[4], acc2, 0, 0, 0);
        acc2 = __builtin_amdgcn_mfma_f32_16x16x32_bf16(a1.s, wf[5], acc2, 0, 0, 0);
        acc3 = __builtin_amdgcn_mfma_f32_16x16x32_bf16(a0.s, wf[6], acc3, 0, 0, 0);
        acc3 = __builtin_amdgcn_mfma_f32_16x16x32_bf16(a1.s, wf[7], acc3, 0, 0, 0);

        // logits partials: lane holds Y[edge=4g+rr][n=t*16+idx] at acc_t[rr]
        float p0[4] = {0.f, 0.f, 0.f, 0.f};
        float p1[4] = {0.f, 0.f, 0.f, 0.f};
#pragma unroll
        for (int rr = 0; rr < 4; ++rr) {
            float yv;
            yv = fmaxf(acc0[rr], 0.f); p0[rr] = fmaf(yv, wf0[0], p0[rr]); p1[rr] = fmaf(yv, wf1[0], p1[rr]);
            yv = fmaxf(acc1[rr], 0.f); p0[rr] = fmaf(yv, wf0[1], p0[rr]); p1[rr] = fmaf(yv, wf1[1], p1[rr]);
            yv = fmaxf(acc2[rr], 0.f); p0[rr] = fmaf(yv, wf0[2], p0[rr]); p1[rr] = fmaf(yv, wf1[2], p1[rr]);
            yv = fmaxf(acc3[rr], 0.f); p0[rr] = fmaf(yv, wf0[3], p0[rr]); p1[rr] = fmaf(yv, wf1[3], p1[rr]);
        }
        // reduce over the 16 lanes of the group (n dimension)
#pragma unroll
        for (int mask = 1; mask < 16; mask <<= 1) {
#pragma unroll
            for (int rr = 0; rr < 4; ++rr) {
                p0[rr] += __shfl_xor(p0[rr], mask, 16);
                p1[rr] += __shfl_xor(p1[rr], mask, 16);
            }
        }

        // softmax + write: lanes idx<8 write prob (edge 4g+rr, class cc)
        {
            int rr = (idx >> 1) & 3, cc = idx & 1;
            float l0 = (rr == 0 ? p0[0] : rr == 1 ? p0[1] : rr == 2 ? p0[2] : p0[3]) + bf0;
            float l1 = (rr == 0 ? p1[0] : rr == 1 ? p1[1] : rr == 2 ? p1[2] : p1[3]) + bf1;
            float mx = fmaxf(l0, l1);
            float e0 = __expf(l0 - mx);
            float e1 = __expf(l1 - mx);
            float v = (cc ? e1 : e0) / (e0 + e1);
            int eo = base + 4 * g + rr;
            if (idx < 8 && eo < E) out[(size_t)eo * 2 + cc] = v;
        }
        // labels output (one 16-lane group handles the 16 edges)
        if (g == 0 && eok) out[(size_t)2 * E + e] = (float)labels[r];
    }
}

extern "C" void kernel_launch(void* const* d_in, const int* in_sizes, int n_in,
                              void* d_out, int out_size, void* d_ws, size_t ws_size,
                              hipStream_t stream) {
    const float* pcd      = (const float*)d_in[0];
    const float* feats    = (const float*)d_in[1];
    const float* also_pts = (const float*)d_in[2];
    const int*   labels   = (const int*)d_in[3];
    const int*   row      = (const int*)d_in[4];
    const int*   col      = (const int*)d_in[5];
    const float* w_in     = (const float*)d_in[6];
    const float* b_in     = (const float*)d_in[7];
    const float* w1       = (const float*)d_in[8];
    const float* b1       = (const float*)d_in[9];
    const float* w2       = (const float*)d_in[10];
    const float* b2       = (const float*)d_in[11];
    const float* w_out    = (const float*)d_in[12];
    const float* b_out    = (const float*)d_in[13];

    int N = in_sizes[0] / 3;
    int M = in_sizes[2] / 3;
    int E = in_sizes[4];

    __hip_bfloat16* Sb = (__hip_bfloat16*)d_ws;
    __hip_bfloat16* Qb = Sb + (size_t)N * 64;
    short*  w1f   = (short*)(Qb + (size_t)M * 64);
    float*  wfold = (float*)(w1f + 4096);
    float*  bfold = wfold + 128;

    int gS = (N * 64 + 255) / 256;
    int gQ = (M * 64 + 255) / 256;
    precompute_S<<<gS, 256, 0, stream>>>(feats, pcd, w_in, Sb, N);
    precompute_Q<<<gQ, 256, 0, stream>>>(also_pts, w_in, b_in, Qb, M);
    pack_w1<<<16, 256, 0, stream>>>(w1, w1f);
    fold_wout<<<1, 256, 0, stream>>>(w2, w_out, b2, b_out, wfold, bfold);

    int ngroups = (E + 15) / 16;
    int blocks = 1536;
    edge_mfma<<<blocks, 256, 0, stream>>>(Sb, Qb, row, col, labels,
                                          (const short8v*)w1f, wfold, bfold, b1,
                                          (float*)d_out, E, ngroups);
}

// Round 4
// 150.835 us; speedup vs baseline: 6.2499x; 1.4499x over previous
//
#include <hip/hip_runtime.h>
#include <hip/hip_bf16.h>

// ---------------------------------------------------------------------------
// AlsoDecoder via algebraic folding + fp16 MFMA:
//   x1 = concat(feats[col], also_pts[row]-pcd[col]) @ w_in + b_in
//      = S[col] + Q[row]                 (S,Q precomputed per point, fp16)
//   y  = relu(x1) @ W1 + b1              (mfma_f32_16x16x32_f16, swapped
//                                         operands so edge = lane&15 in D)
//   logits = relu(y) @ (W2@W_out) + (b2@W_out + b_out)   (layer 3 folded)
//   probs = softmax(logits)
// Edge kernel per 16-edge group: gather S/Q rows (v_pk_add/max_f16 repack),
// 8 MFMAs, lane-local logit fold, 2-step shuffle reduce, softmax, label copy.
// ---------------------------------------------------------------------------

typedef _Float16 half8 __attribute__((ext_vector_type(8)));
typedef __attribute__((ext_vector_type(4))) float f32x4;

union U84h { uint4 u; half8 h; };
union U24h { uint2 u; _Float16 h[4]; };

__device__ __forceinline__ half8 relu8(half8 v) {
    half8 z;
#pragma unroll
    for (int i = 0; i < 8; ++i) z[i] = (_Float16)0.f;
    return __builtin_elementwise_max(v, z);
}

// ---------------- prep kernels -------------------------------------------
// S[p][4jq..4jq+3] = feats[p]@W_f - pcd[p]@W_p   (4 outputs per thread)
__global__ __launch_bounds__(256) void precompute_S(
    const float* __restrict__ feats, const float* __restrict__ pcd,
    const float* __restrict__ w_in, _Float16* __restrict__ S, int N) {
    int t = blockIdx.x * 256 + threadIdx.x;
    int p = t >> 4, jq = t & 15;
    if (p >= N) return;
    const float* f = feats + (size_t)p * 64;
    float4 acc = make_float4(0.f, 0.f, 0.f, 0.f);
#pragma unroll 8
    for (int k = 0; k < 64; ++k) {
        float fv = f[k];
        float4 w = *(const float4*)(w_in + k * 64 + jq * 4);
        acc.x = fmaf(fv, w.x, acc.x);
        acc.y = fmaf(fv, w.y, acc.y);
        acc.z = fmaf(fv, w.z, acc.z);
        acc.w = fmaf(fv, w.w, acc.w);
    }
    const float* pp = pcd + (size_t)p * 3;
#pragma unroll
    for (int k = 0; k < 3; ++k) {
        float fv = -pp[k];
        float4 w = *(const float4*)(w_in + (64 + k) * 64 + jq * 4);
        acc.x = fmaf(fv, w.x, acc.x);
        acc.y = fmaf(fv, w.y, acc.y);
        acc.z = fmaf(fv, w.z, acc.z);
        acc.w = fmaf(fv, w.w, acc.w);
    }
    U24h o;
    o.h[0] = (_Float16)acc.x; o.h[1] = (_Float16)acc.y;
    o.h[2] = (_Float16)acc.z; o.h[3] = (_Float16)acc.w;
    *(uint2*)(S + (size_t)p * 64 + jq * 4) = o.u;
}

// Q[m][4jq..4jq+3] = also_pts[m]@W_p + b_in
__global__ __launch_bounds__(256) void precompute_Q(
    const float* __restrict__ also_pts, const float* __restrict__ w_in,
    const float* __restrict__ b_in, _Float16* __restrict__ Q, int M) {
    int t = blockIdx.x * 256 + threadIdx.x;
    int m = t >> 4, jq = t & 15;
    if (m >= M) return;
    const float* q = also_pts + (size_t)m * 3;
    float4 acc = *(const float4*)(b_in + jq * 4);
#pragma unroll
    for (int k = 0; k < 3; ++k) {
        float fv = q[k];
        float4 w = *(const float4*)(w_in + (64 + k) * 64 + jq * 4);
        acc.x = fmaf(fv, w.x, acc.x);
        acc.y = fmaf(fv, w.y, acc.y);
        acc.z = fmaf(fv, w.z, acc.z);
        acc.w = fmaf(fv, w.w, acc.w);
    }
    U24h o;
    o.h[0] = (_Float16)acc.x; o.h[1] = (_Float16)acc.y;
    o.h[2] = (_Float16)acc.z; o.h[3] = (_Float16)acc.w;
    *(uint2*)(Q + (size_t)m * 64 + jq * 4) = o.u;
}

// Pack W1 into per-lane fragment order (used as the MFMA *A* operand:
// A'[row=n][k] = W1[k][n]; frag f = ntile*2+kstep, slot (lane,j) <-
// W1[kstep*32 + 8*(lane>>4) + j][ntile*16 + (lane&15)]).
// Also fold layer 3: wf0/wf1[n] = sum_j W2[n][j]*Wout[j][c]; bf[c] folded bias.
__global__ __launch_bounds__(256) void pack_fold(
    const float* __restrict__ w1, const float* __restrict__ w2,
    const float* __restrict__ w_out, const float* __restrict__ b2,
    const float* __restrict__ b_out,
    _Float16* __restrict__ w1f, float* __restrict__ wf0,
    float* __restrict__ wf1, float* __restrict__ bf) {
    int t = blockIdx.x * 256 + threadIdx.x;
    if (t < 4096) {
        int f = t >> 9, lane = (t >> 3) & 63, j = t & 7;
        int ntile = f >> 1, kstep = f & 1;
        int k = kstep * 32 + ((lane >> 4) << 3) + j;
        int n = ntile * 16 + (lane & 15);
        w1f[t] = (_Float16)w1[k * 64 + n];
    } else if (t < 4160) {
        int n = t - 4096;
        float a0 = 0.f, a1 = 0.f;
#pragma unroll
        for (int j = 0; j < 64; ++j) {
            a0 = fmaf(w2[n * 64 + j], w_out[j * 2 + 0], a0);
            a1 = fmaf(w2[n * 64 + j], w_out[j * 2 + 1], a1);
        }
        wf0[n] = a0; wf1[n] = a1;
    } else if (t == 4160) {
        float a0 = b_out[0], a1 = b_out[1];
#pragma unroll
        for (int j = 0; j < 64; ++j) {
            a0 = fmaf(b2[j], w_out[j * 2 + 0], a0);
            a1 = fmaf(b2[j], w_out[j * 2 + 1], a1);
        }
        bf[0] = a0; bf[1] = a1;
    }
}

// ---------------- edge kernel --------------------------------------------
__global__ __launch_bounds__(256, 4) void edge_mfma(
    const _Float16* __restrict__ S, const _Float16* __restrict__ Q,
    const int* __restrict__ row, const int* __restrict__ col,
    const int* __restrict__ labels,
    const half8* __restrict__ w1frag,     // [8 frags][64 lanes] half8
    const float* __restrict__ wf0, const float* __restrict__ wf1,
    const float* __restrict__ bfold, const float* __restrict__ b1,
    float* __restrict__ out, int E, int ngroups) {
    int lane = threadIdx.x & 63;
    int idx  = lane & 15;          // edge-in-group (D col)
    int g    = lane >> 4;
    int gwave  = blockIdx.x * 4 + (threadIdx.x >> 6);
    int nwaves = gridDim.x * 4;

    // W1 fragments (A operand) held in registers across the loop
    half8 wf[8];
#pragma unroll
    for (int f = 0; f < 8; ++f) wf[f] = w1frag[f * 64 + lane];
    // per-lane n-slice constants: n = tt*16 + 4*g + reg
    f32x4 b1v[4], w0v[4], w1v[4];
#pragma unroll
    for (int tt = 0; tt < 4; ++tt) {
        b1v[tt] = *(const f32x4*)(b1 + tt * 16 + 4 * g);
        w0v[tt] = *(const f32x4*)(wf0 + tt * 16 + 4 * g);
        w1v[tt] = *(const f32x4*)(wf1 + tt * 16 + 4 * g);
    }
    float bf0 = bfold[0], bf1 = bfold[1];

    for (int grp = gwave; grp < ngroups; grp += nwaves) {
        int base = grp << 4;
        int e = base + idx;
        bool eok = (e < E);
        int esafe = eok ? e : (E - 1);
        int r = row[esafe];
        int c = col[esafe];

        // gather + x = relu(S[c]+Q[r]) via packed fp16 math (B operand:
        // B[k][col=edge]: lane holds edge=lane&15, k = kstep*32 + 8*g + j)
        const uint4* sp = (const uint4*)(S + (size_t)c * 64);
        const uint4* qp = (const uint4*)(Q + (size_t)r * 64);
        U84h s0, q0, s1, q1;
        s0.u = sp[g];     q0.u = qp[g];
        s1.u = sp[4 + g]; q1.u = qp[4 + g];
        half8 x0 = relu8(s0.h + q0.h);
        half8 x1 = relu8(s1.h + q1.h);

        // D = W1'·X: lane holds Y[n = tt*16+4g+reg][edge=idx] in acc[tt][reg]
        f32x4 acc[4];
#pragma unroll
        for (int tt = 0; tt < 4; ++tt) {
            acc[tt] = b1v[tt];
            acc[tt] = __builtin_amdgcn_mfma_f32_16x16x32_f16(wf[2 * tt],     x0, acc[tt], 0, 0, 0);
            acc[tt] = __builtin_amdgcn_mfma_f32_16x16x32_f16(wf[2 * tt + 1], x1, acc[tt], 0, 0, 0);
        }

        // logits: lane-local fold over its 16 n-values, then reduce 4 lanes
        float p0 = 0.f, p1 = 0.f;
#pragma unroll
        for (int tt = 0; tt < 4; ++tt)
#pragma unroll
            for (int reg = 0; reg < 4; ++reg) {
                float yv = fmaxf(acc[tt][reg], 0.f);
                p0 = fmaf(yv, w0v[tt][reg], p0);
                p1 = fmaf(yv, w1v[tt][reg], p1);
            }
        p0 += __shfl_xor(p0, 16); p0 += __shfl_xor(p0, 32);
        p1 += __shfl_xor(p1, 16); p1 += __shfl_xor(p1, 32);

        if (g == 0 && eok) {
            float l0 = p0 + bf0, l1 = p1 + bf1;
            float mx = fmaxf(l0, l1);
            float e0 = __expf(l0 - mx);
            float e1 = __expf(l1 - mx);
            float inv = 1.f / (e0 + e1);
            *(float2*)(out + (size_t)e * 2) = make_float2(e0 * inv, e1 * inv);
            out[(size_t)2 * E + e] = (float)labels[r];
        }
    }
}

extern "C" void kernel_launch(void* const* d_in, const int* in_sizes, int n_in,
                              void* d_out, int out_size, void* d_ws, size_t ws_size,
                              hipStream_t stream) {
    const float* pcd      = (const float*)d_in[0];
    const float* feats    = (const float*)d_in[1];
    const float* also_pts = (const float*)d_in[2];
    const int*   labels   = (const int*)d_in[3];
    const int*   row      = (const int*)d_in[4];
    const int*   col      = (const int*)d_in[5];
    const float* w_in     = (const float*)d_in[6];
    const float* b_in     = (const float*)d_in[7];
    const float* w1       = (const float*)d_in[8];
    const float* b1       = (const float*)d_in[9];
    const float* w2       = (const float*)d_in[10];
    const float* b2       = (const float*)d_in[11];
    const float* w_out    = (const float*)d_in[12];
    const float* b_out    = (const float*)d_in[13];

    int N = in_sizes[0] / 3;
    int M = in_sizes[2] / 3;
    int E = in_sizes[4];

    _Float16* Sb = (_Float16*)d_ws;
    _Float16* Qb = Sb + (size_t)N * 64;
    _Float16* w1f = Qb + (size_t)M * 64;
    float* wf0 = (float*)(w1f + 4096);
    float* wf1 = wf0 + 64;
    float* bf  = wf1 + 64;

    int gS = (N * 16 + 255) / 256;
    int gQ = (M * 16 + 255) / 256;
    precompute_S<<<gS, 256, 0, stream>>>(feats, pcd, w_in, Sb, N);
    precompute_Q<<<gQ, 256, 0, stream>>>(also_pts, w_in, b_in, Qb, M);
    pack_fold<<<17, 256, 0, stream>>>(w1, w2, w_out, b2, b_out, w1f, wf0, wf1, bf);

    int ngroups = (E + 15) / 16;
    edge_mfma<<<2048, 256, 0, stream>>>(Sb, Qb, row, col, labels,
                                        (const half8*)w1f, wf0, wf1, bf, b1,
                                        (float*)d_out, E, ngroups);
}